// Round 17
// baseline (267.788 us; speedup 1.0000x reference)
//
#include <hip/hip_runtime.h>

// LSTM: B=1024, S=512, E=H=50, fp32 in/out.
// Grid: 512 blocks x 256 threads (4 waves). Each block owns 2 chains for all 512 steps.
// -> 2 blocks/CU, 2 waves/SIMD from DIFFERENT blocks (independent barrier domains): when one
//    block stalls (barrier / LDS latency / trans chain), the other issues. No duplicated work:
//    13 M-tiles split {4,3,3,3} across the 4 waves; B-operand cols = 2 real chains.
// gates(16x16 tiles) = W_reordered(208x128, fp16 in VGPRs) @ [x;h] (128x16, fp16 in LDS).
// Gate reorder j = h*4 + g -> lane (kg,m)'s acc_i regs = {i,f,g,o} of cell (chain=m, h=4*mt+kg).
// B-operand ds_reads masked to m<2 (cols 2-15 zero). Tile-i gates spread to lanes m=2i,2i+1 via
// DPP row_shr:2i (R14-verified: lane i reads lane i-N) + 2-level cndmask select.
// Each active lane runs ONE 10-trans cell chain. x-part of t+1 prefetched via xcur.
// x staging: waves 2-3, one (chain,e)/thread, 4-slot ring, FOUR-register rotation (R4-proven):
// step(t,P,Q) issues Q<-x[t+4] (Q = reg written at t+2) and writes P=x[t+2] at bottom.
// (R15 bug: 2-reg rotation clobbered x[t+3] with x[t+4] before staging.)

typedef __attribute__((ext_vector_type(8))) _Float16 f16x8;  // 8 x fp16 (4 VGPRs) MFMA operand
typedef __attribute__((ext_vector_type(4))) float f32x4;

__device__ __forceinline__ float fast_sigmoid(float z) {
  return __builtin_amdgcn_rcpf(1.0f + __expf(-z));
}
__device__ __forceinline__ float fast_tanh(float z) {
  return 1.0f - 2.0f * __builtin_amdgcn_rcpf(1.0f + __expf(2.0f * z));
}

__global__ __launch_bounds__(256, 2) void lstm_fused(
    const float* __restrict__ xg,     // (1024, 512, 50)
    const float* __restrict__ W_ih,   // (200, 50)
    const float* __restrict__ W_hh,   // (200, 50)
    const float* __restrict__ b_ih,   // (200,)
    const float* __restrict__ b_hh,   // (200,)
    float* __restrict__ out)          // (1024, 1, 50)
{
  constexpr int S = 512, E = 50, H = 50;
  const int tid  = threadIdx.x;
  const int lane = tid & 63;
  const int wv   = tid >> 6;          // 0..3
  const int c0   = blockIdx.x << 1;   // 2 chains per block

  // LDS: xbuf ring[4 slots][2 kt][4 chain-slots][64B] = 2048 B @0  (chain slots 2,3 stay zero)
  //      hbuf ring[2 slots][2 kt][4 chain-slots][64B] = 1024 B @2048
  __shared__ __align__(16) unsigned char lds[3072];
  for (int i = tid; i < 3072 / 4; i += 256) reinterpret_cast<unsigned*>(lds)[i] = 0u;

  const int m  = lane & 15;   // A m-index / D col
  const int kg = lane >> 4;   // k-group of 8; D row-group (h-sub)
  const int  tstart = (wv == 0) ? 0 : (4 + 3 * (wv - 1));   // {0,4,7,10}
  const int  ntiles = (wv == 0) ? 4 : 3;
  const bool four   = (wv == 0);

  // ---- W fragments: register-stationary fp16 (up to 4 tiles/wave) ----
  f16x8 wfr[4][4];
  f32x4 bias[4];
#pragma unroll
  for (int i = 0; i < 4; ++i) {
    const int  mt    = tstart + i;
    const bool tv    = (i < ntiles);
    const int  j     = mt * 16 + m;     // reordered gate idx = h*4 + g
    const int  hh    = j >> 2, g = j & 3;
    const bool rowok = tv && (hh < H);
#pragma unroll
    for (int kt = 0; kt < 4; ++kt) {
      f16x8 s;
#pragma unroll
      for (int jj = 0; jj < 8; ++jj) {
        const int k = kt * 32 + kg * 8 + jj;
        float w = 0.0f;
        if (rowok) {
          if (k < 50)                  w = W_ih[(g * 50 + hh) * 50 + k];
          else if (k >= 64 && k < 114) w = W_hh[(g * 50 + hh) * 50 + (k - 64)];
        }
        s[jj] = (_Float16)w;
      }
      wfr[i][kt] = s;
    }
    f32x4 bv;
#pragma unroll
    for (int r = 0; r < 4; ++r) {
      const int jr = mt * 16 + kg * 4 + r;
      const int hr = jr >> 2, gr = jr & 3;
      bv[r] = (tv && hr < H) ? (b_ih[gr * 50 + hr] + b_hh[gr * 50 + hr]) : 0.0f;
    }
    bias[i] = bv;
  }

  float cst = 0.0f;   // c state: lane (kg, m<2*ntiles) owns cell (chain=m&1, h=4*(tstart+(m>>1))+kg)

  // ---- x staging: waves 2-3, threads ts<100 own one (chain,e) each ----
  const int  ts    = tid - 128;
  const bool sok   = (wv >= 2) && (ts >= 0) && (ts < 100);
  const int  schn  = sok ? (ts / 50) : 0;
  const int  se    = sok ? (ts - 50 * schn) : 0;
  const long gb    = ((long)(c0 + schn) * S) * E + se;
  const unsigned la = (unsigned)(((se >> 5) << 8) + (schn << 6) + ((se & 31) << 1));
  float A = 0.f, B = 0.f, C = 0.f, D = 0.f;

  __syncthreads();   // zeros visible (pads + h0 = 0)

  if (sok) {
    *reinterpret_cast<_Float16*>(lds + 0 * 512 + la) = (_Float16)xg[gb + 0 * E];
    *reinterpret_cast<_Float16*>(lds + 1 * 512 + la) = (_Float16)xg[gb + 1 * E];
    A = xg[gb + 2 * E];
    B = xg[gb + 3 * E];
  }
  __syncthreads();   // x slots 0,1 staged

  const unsigned bro = (unsigned)(((lane & 1) << 6) + (kg << 4));

  // B-operand registers: persistent, zero for lanes m>=2 (masked loads keep cols 2-15 zero)
  f16x8 b2{}, b3{}, nb0{}, nb1{};

  // ---- prime xcur = bias + W_x @ x[0] (slot 0) ----
  f32x4 xcur[4];
  {
    if (m < 2) {
      nb0 = *reinterpret_cast<const f16x8*>(lds + 0u + bro);
      nb1 = *reinterpret_cast<const f16x8*>(lds + 256u + bro);
    }
#pragma unroll
    for (int i = 0; i < 3; ++i) {
      f32x4 a = bias[i];
      a = __builtin_amdgcn_mfma_f32_16x16x32_f16(wfr[i][0], nb0, a, 0, 0, 0);
      a = __builtin_amdgcn_mfma_f32_16x16x32_f16(wfr[i][1], nb1, a, 0, 0, 0);
      xcur[i] = a;
    }
    xcur[3] = bias[3];
    if (four) {
      f32x4 a = bias[3];
      a = __builtin_amdgcn_mfma_f32_16x16x32_f16(wfr[3][0], nb0, a, 0, 0, 0);
      a = __builtin_amdgcn_mfma_f32_16x16x32_f16(wfr[3][1], nb1, a, 0, 0, 0);
      xcur[3] = a;
    }
  }

  auto step = [&](int t, float& P, float& Q) {
    // issue x[t+4] early into Q (the register written as x[(t+2)+2] two steps later)
    if (sok && (t + 4) < S) Q = xg[gb + (long)(t + 4) * E];

    const unsigned hs = 2048u + (unsigned)(t & 1) * 512u;
    const unsigned xs = (unsigned)((t + 1) & 3) * 512u;
    if (m < 2) {   // only real chain columns read; cols 2-15 stay zero
      b2  = *reinterpret_cast<const f16x8*>(lds + hs + bro);
      b3  = *reinterpret_cast<const f16x8*>(lds + hs + 256u + bro);
      nb0 = *reinterpret_cast<const f16x8*>(lds + xs + bro);
      nb1 = *reinterpret_cast<const f16x8*>(lds + xs + 256u + bro);
    }

    // critical path: h-part, chain depth 2, C-in = precomputed x-part
    f32x4 acc[4];
#pragma unroll
    for (int i = 0; i < 3; ++i) {
      f32x4 a = xcur[i];
      a = __builtin_amdgcn_mfma_f32_16x16x32_f16(wfr[i][2], b2, a, 0, 0, 0);
      a = __builtin_amdgcn_mfma_f32_16x16x32_f16(wfr[i][3], b3, a, 0, 0, 0);
      acc[i] = a;
    }
    acc[3] = xcur[3];
    if (four) {
      f32x4 a = xcur[3];
      a = __builtin_amdgcn_mfma_f32_16x16x32_f16(wfr[3][2], b2, a, 0, 0, 0);
      a = __builtin_amdgcn_mfma_f32_16x16x32_f16(wfr[3][3], b3, a, 0, 0, 0);
      acc[3] = a;
    }

    // spread tile-i gates (lanes m=0,1) to lanes m=2i,2i+1 (row_shr:2i, verified direction)
    float gv[4];
#pragma unroll
    for (int r = 0; r < 4; ++r) {
      const int s1 = __builtin_amdgcn_update_dpp(
          0, __float_as_int(acc[1][r]), 0x112 /*row_shr:2*/, 0xF, 0xF, true);
      const int s2 = __builtin_amdgcn_update_dpp(
          0, __float_as_int(acc[2][r]), 0x114 /*row_shr:4*/, 0xF, 0xF, true);
      const int s3 = __builtin_amdgcn_update_dpp(
          0, __float_as_int(acc[3][r]), 0x116 /*row_shr:6*/, 0xF, 0xF, true);
      const float lo = (m & 2) ? __int_as_float(s1) : acc[0][r];
      const float hi = (m & 2) ? __int_as_float(s3) : __int_as_float(s2);
      gv[r] = (m & 4) ? hi : lo;
    }

    // one cell chain per lane: lanes (kg, m<2*ntiles), tile i=m>>1, chain m&1
    const int ti = m >> 1;
    const int h  = 4 * (tstart + ti) + kg;
    if ((m < 2 * ntiles) && (h < H)) {
      const float ig = fast_sigmoid(gv[0]);
      const float fg = fast_sigmoid(gv[1]);
      const float gg = fast_tanh   (gv[2]);
      const float og = fast_sigmoid(gv[3]);
      const float c  = fg * cst + ig * gg;
      cst = c;
      const float hv = og * fast_tanh(c);
      const int ch = m & 1;
      if (t == S - 1) {
        out[(long)(c0 + ch) * H + h] = hv;
      } else {
        *reinterpret_cast<_Float16*>(
            lds + 2048u + (unsigned)((t + 1) & 1) * 512u +
            (unsigned)(((h >> 5) << 8) + (ch << 6) + ((h & 31) << 1))) = (_Float16)hv;
      }
    }

    // off-critical-path: x-part for step t+1
#pragma unroll
    for (int i = 0; i < 3; ++i) {
      f32x4 a = bias[i];
      a = __builtin_amdgcn_mfma_f32_16x16x32_f16(wfr[i][0], nb0, a, 0, 0, 0);
      a = __builtin_amdgcn_mfma_f32_16x16x32_f16(wfr[i][1], nb1, a, 0, 0, 0);
      xcur[i] = a;
    }
    if (four) {
      f32x4 a = bias[3];
      a = __builtin_amdgcn_mfma_f32_16x16x32_f16(wfr[3][0], nb0, a, 0, 0, 0);
      a = __builtin_amdgcn_mfma_f32_16x16x32_f16(wfr[3][1], nb1, a, 0, 0, 0);
      xcur[3] = a;
    }

    // write x[t+2] (issued 2 steps ago into P) into its ring slot
    if (sok && (t + 2) < S) {
      *reinterpret_cast<_Float16*>(lds + (unsigned)((t + 2) & 3) * 512u + la) = (_Float16)P;
    }
    __syncthreads();   // h slot (t+1)&1 and x slot (t+2)&3 complete
  };

  for (int t = 0; t < S; t += 4) {
    step(t + 0, A, C);
    step(t + 1, B, D);
    step(t + 2, C, A);
    step(t + 3, D, B);
  }
}

extern "C" void kernel_launch(void* const* d_in, const int* in_sizes, int n_in,
                              void* d_out, int out_size, void* d_ws, size_t ws_size,
                              hipStream_t stream) {
  const float* x    = (const float*)d_in[0];
  const float* W_ih = (const float*)d_in[1];
  const float* W_hh = (const float*)d_in[2];
  const float* b_ih = (const float*)d_in[3];
  const float* b_hh = (const float*)d_in[4];
  float* out = (float*)d_out;
  hipLaunchKernelGGL(lstm_fused, dim3(512), dim3(256), 0, stream,
                     x, W_ih, W_hh, b_ih, b_hh, out);
}

// Round 21
// 201.765 us; speedup vs baseline: 1.3272x; 1.3272x over previous
//
#include <hip/hip_runtime.h>

// LSTM: B=1024, S=512, E=H=50, fp32 in/out.
// Grid: 256 blocks x 512 threads (8 waves). Each block owns 4 chains for all 512 steps (1 block/CU).
// Waves 0-5: 2 M-tiles; wave 6: 1; wave 7: x-stager. 13 tiles cover 208 reordered gate rows.
// gates = W_reordered(208x128 fp16 VGPRs) @ [x;h](128x16 fp16 LDS); j=h*4+g reorder ->
// lane (kg,m) acc regs = {i,f,g,o} of cell (chain=m, h=4*mt+kg).
// TIME-BATCHED x-projection, all-static rewrite of R18 (suspected compiler hazard: persistent
// regs divergently written under runtime-p branch; rules #19/#20):
//  - 6-step unrolled loop: batch at positions 2,5 (t%3==2); xc set and stager reg static/position.
//  - batch(t): ALL lanes load x slots (t+gg)&3 (gg=max(1,m>>2); lanes m<4 duplicate group 1 ->
//    dead cols), fresh local operands, 4 MFMA -> xacc cols 4-15 = x-proj of steps t+1..t+3,
//    then DPP row_shl:4/8/12 (R13-verified: shl:N reads lane+N) extracts into xcA/xcB/xcC.
//  - prologue = batch(-1) (slots 0,1,2) + barrier before stager's t=0 slot-0 overwrite.
// h-part per step: 2 chained MFMA, C-in = xc (critical path); act on lanes m<8 via row_shr:4
// (R14-verified); h fp16 -> 2-slot LDS ring; single barrier/step.
// Stager: R0 even-t / R1 odd-t, write x[t+4] into slot t&3 then reload x[t+6] (write-before-load).

typedef __attribute__((ext_vector_type(8))) _Float16 f16x8;  // 8 x fp16 (4 VGPRs) MFMA operand
typedef __attribute__((ext_vector_type(4))) float f32x4;

__device__ __forceinline__ float fast_sigmoid(float z) {
  return __builtin_amdgcn_rcpf(1.0f + __expf(-z));
}
__device__ __forceinline__ float fast_tanh(float z) {
  return 1.0f - 2.0f * __builtin_amdgcn_rcpf(1.0f + __expf(2.0f * z));
}

__global__ __launch_bounds__(512, 1) void lstm_fused(
    const float* __restrict__ xg,     // (1024, 512, 50)
    const float* __restrict__ W_ih,   // (200, 50)
    const float* __restrict__ W_hh,   // (200, 50)
    const float* __restrict__ b_ih,   // (200,)
    const float* __restrict__ b_hh,   // (200,)
    float* __restrict__ out)          // (1024, 1, 50)
{
  constexpr int S = 512, E = 50, H = 50;
  const int tid  = threadIdx.x;
  const int lane = tid & 63;
  const int wv   = tid >> 6;
  const int c0   = blockIdx.x << 2;   // 4 chains per block

  // LDS: xbuf ring[4 slots][2 kt][4 chains][64B] = 2048 B @0
  //      hbuf ring[2 slots][2 kt][4 chains][64B] = 1024 B @2048
  __shared__ __align__(16) unsigned char lds[3072];
  for (int i = tid; i < 3072 / 4; i += 512) reinterpret_cast<unsigned*>(lds)[i] = 0u;

  const int m  = lane & 15;   // A m-index / D col
  const int kg = lane >> 4;   // k-group of 8; D row-group (h-sub)
  const int tstart = 2 * wv;
  const int ntiles = (wv < 6) ? 2 : ((wv == 6) ? 1 : 0);

  // ---- W fragments: x-part (kt0,1) and h-part (kt2,3), register-stationary fp16 ----
  f16x8 wxf[2][2], whf[2][2];
  f32x4 bias[2];
#pragma unroll
  for (int i = 0; i < 2; ++i) {
    const int  mt    = tstart + i;
    const bool tv    = (i < ntiles);
    const int  j     = mt * 16 + m;     // reordered gate idx = h*4 + g
    const int  hh    = j >> 2, g = j & 3;
    const bool rowok = tv && (hh < H);
#pragma unroll
    for (int kt = 0; kt < 4; ++kt) {
      f16x8 s;
#pragma unroll
      for (int jj = 0; jj < 8; ++jj) {
        const int k = kt * 32 + kg * 8 + jj;
        float w = 0.0f;
        if (rowok) {
          if (k < 50)                  w = W_ih[(g * 50 + hh) * 50 + k];
          else if (k >= 64 && k < 114) w = W_hh[(g * 50 + hh) * 50 + (k - 64)];
        }
        s[jj] = (_Float16)w;
      }
      if (kt < 2) wxf[i][kt] = s; else whf[i][kt - 2] = s;
    }
    f32x4 bv;
#pragma unroll
    for (int r = 0; r < 4; ++r) {
      const int jr = mt * 16 + kg * 4 + r;
      const int hr = jr >> 2, gr = jr & 3;
      bv[r] = (tv && hr < H) ? (b_ih[gr * 50 + hr] + b_hh[gr * 50 + hr]) : 0.0f;
    }
    bias[i] = bv;
  }

  float cst = 0.0f;   // c state: lane (kg, m<8) owns cell (chain=m&3, h=4*(tstart+(m>>2))+kg)

  // ---- wave 7: x stagers (4 (chain,e) slots per lane) ----
  const bool isstg = (wv == 7);
  bool sok[4]; long gb[4]; unsigned la[4];
  float R0[4], R1[4];                  // R0 written at even t, R1 at odd t
#pragma unroll
  for (int u = 0; u < 4; ++u) {
    const int xs = lane + 64 * u;
    sok[u] = isstg && (xs < 200);
    const int chn = sok[u] ? (xs / 50) : 0;
    const int e   = sok[u] ? (xs - 50 * chn) : 0;
    gb[u] = ((long)(c0 + chn) * S) * E + e;
    la[u] = (unsigned)(((e >> 5) << 8) + (chn << 6) + ((e & 31) << 1));
    R0[u] = 0.f; R1[u] = 0.f;
  }

  __syncthreads();   // zeros visible (pads + h0 = 0)

  // prime x slots 0..3 = x[0..3]; preload R0 = x[4] (written t=0), R1 = x[5] (t=1)
#pragma unroll
  for (int u = 0; u < 4; ++u) {
    if (sok[u]) {
#pragma unroll
      for (int sl = 0; sl < 4; ++sl)
        *reinterpret_cast<_Float16*>(lds + sl * 512 + la[u]) = (_Float16)xg[gb[u] + sl * E];
    }
  }
#pragma unroll
  for (int u = 0; u < 4; ++u) {
    if (sok[u]) { R0[u] = xg[gb[u] + 4 * E]; R1[u] = xg[gb[u] + 5 * E]; }
  }
  __syncthreads();   // x slots 0..3 staged

  const unsigned bro = (unsigned)(((lane & 3) << 6) + (kg << 4));   // h-read addr (m<4)
  f16x8 b2{}, b3{};   // persistent h operands; lanes m>=4 stay zero (cols 4-15 dead)

  f32x4 xcA[2], xcB[2], xcC[2];   // x-projection for next steps t+1 / t+2 / t+3

  // batch(t): xacc cols 4-15 = bias + W_x @ x[t+1..t+3]; extract to xcA/B/C (cols 0-3 dead dup).
  auto batch = [&](int t) {
    const int g  = m >> 2;
    const int gg = g ? g : 1;          // lanes m<4 duplicate group 1 (same-addr broadcast)
    const unsigned xa = (unsigned)(((t + gg) & 3) * 512 + ((m & 3) << 6) + (kg << 4));
    const f16x8 nbA = *reinterpret_cast<const f16x8*>(lds + xa);          // k 0-31
    const f16x8 nbB = *reinterpret_cast<const f16x8*>(lds + xa + 256u);   // k 32-63
    f32x4 x0 = bias[0];
    x0 = __builtin_amdgcn_mfma_f32_16x16x32_f16(wxf[0][0], nbA, x0, 0, 0, 0);
    x0 = __builtin_amdgcn_mfma_f32_16x16x32_f16(wxf[0][1], nbB, x0, 0, 0, 0);
    f32x4 x1 = bias[1];
    x1 = __builtin_amdgcn_mfma_f32_16x16x32_f16(wxf[1][0], nbA, x1, 0, 0, 0);
    x1 = __builtin_amdgcn_mfma_f32_16x16x32_f16(wxf[1][1], nbB, x1, 0, 0, 0);
#pragma unroll
    for (int r = 0; r < 4; ++r) {      // shl:N -> lane reads lane+N (R13-verified)
      xcA[0][r] = __int_as_float(__builtin_amdgcn_update_dpp(0, __float_as_int(x0[r]), 0x104, 0xF, 0xF, true));
      xcA[1][r] = __int_as_float(__builtin_amdgcn_update_dpp(0, __float_as_int(x1[r]), 0x104, 0xF, 0xF, true));
      xcB[0][r] = __int_as_float(__builtin_amdgcn_update_dpp(0, __float_as_int(x0[r]), 0x108, 0xF, 0xF, true));
      xcB[1][r] = __int_as_float(__builtin_amdgcn_update_dpp(0, __float_as_int(x1[r]), 0x108, 0xF, 0xF, true));
      xcC[0][r] = __int_as_float(__builtin_amdgcn_update_dpp(0, __float_as_int(x0[r]), 0x10C, 0xF, 0xF, true));
      xcC[1][r] = __int_as_float(__builtin_amdgcn_update_dpp(0, __float_as_int(x1[r]), 0x10C, 0xF, 0xF, true));
    }
  };

  if (ntiles > 0) batch(-1);   // prologue: slots (gg-1)&3 = 0,1,2 -> steps 0,1,2
  __syncthreads();             // prologue reads done before stager t=0 overwrites slot 0

  auto step = [&](int t, f32x4 (&xc)[2], float (&SR)[4], bool dobatch, bool last) {
    if (ntiles > 0) {
      const unsigned hs = 2048u + (unsigned)(t & 1) * 512u;
      if (m < 4) {
        b2 = *reinterpret_cast<const f16x8*>(lds + hs + bro);
        b3 = *reinterpret_cast<const f16x8*>(lds + hs + 256u + bro);
      }
      // critical path: h-part, chain depth 2, C-in = pre-extracted x-part
      f32x4 acc0 = xc[0];
      acc0 = __builtin_amdgcn_mfma_f32_16x16x32_f16(whf[0][0], b2, acc0, 0, 0, 0);
      acc0 = __builtin_amdgcn_mfma_f32_16x16x32_f16(whf[0][1], b3, acc0, 0, 0, 0);
      f32x4 acc1 = xc[1];
      acc1 = __builtin_amdgcn_mfma_f32_16x16x32_f16(whf[1][0], b2, acc1, 0, 0, 0);
      acc1 = __builtin_amdgcn_mfma_f32_16x16x32_f16(whf[1][1], b3, acc1, 0, 0, 0);

      if (dobatch) batch(t);   // off-critical-path; xc values already consumed above

      // act: tile0 -> lanes m0-3 (direct), tile1 -> m4-7 (row_shr:4, R14-verified)
      float gv[4];
#pragma unroll
      for (int r = 0; r < 4; ++r) {
        const int sp = __builtin_amdgcn_update_dpp(0, __float_as_int(acc1[r]), 0x114, 0xF, 0xF, true);
        gv[r] = (m < 4) ? acc0[r] : __int_as_float(sp);
      }
      const int ti = m >> 2;
      const int h  = 4 * (tstart + ti) + kg;
      if ((m < 8) && (ti < ntiles) && (h < H)) {
        const float ig = fast_sigmoid(gv[0]);
        const float fg = fast_sigmoid(gv[1]);
        const float gg2 = fast_tanh  (gv[2]);
        const float og = fast_sigmoid(gv[3]);
        const float c  = fg * cst + ig * gg2;
        cst = c;
        const float hv = og * fast_tanh(c);
        const int ch = m & 3;
        if (last) {
          out[(long)(c0 + ch) * H + h] = hv;
        } else {
          *reinterpret_cast<_Float16*>(
              lds + 2048u + (unsigned)((t + 1) & 1) * 512u +
              (unsigned)(((h >> 5) << 8) + (ch << 6) + ((h & 31) << 1))) = (_Float16)hv;
        }
      }
    } else if (isstg) {
      if (t + 4 < S) {   // write x[t+4] into slot t&3 (x[t] dead: last batch-read <= t-1)
        const unsigned sl = (unsigned)(t & 3) * 512u;
#pragma unroll
        for (int u = 0; u < 4; ++u)
          if (sok[u]) *reinterpret_cast<_Float16*>(lds + sl + la[u]) = (_Float16)SR[u];
      }
      if (t + 6 < S) {
#pragma unroll
        for (int u = 0; u < 4; ++u)
          if (sok[u]) SR[u] = xg[gb[u] + (long)(t + 6) * E];
      }
    }
    __syncthreads();   // h slot (t+1)&1, x slot t&3, batch reads all complete
  };

  for (int t0 = 0; t0 + 5 < S; t0 += 6) {   // t0 = 0,6,...,504 -> steps 0..509
    step(t0 + 0, xcA, R0, false, false);
    step(t0 + 1, xcB, R1, false, false);
    step(t0 + 2, xcC, R0, true,  false);    // batch -> steps t0+3,4,5
    step(t0 + 3, xcA, R1, false, false);
    step(t0 + 4, xcB, R0, false, false);
    step(t0 + 5, xcC, R1, true,  false);    // batch -> steps t0+6,7,8
  }
  step(S - 2, xcA, R0, false, false);       // 510 (from batch at 509)
  step(S - 1, xcB, R1, false, true);        // 511 -> out
}

extern "C" void kernel_launch(void* const* d_in, const int* in_sizes, int n_in,
                              void* d_out, int out_size, void* d_ws, size_t ws_size,
                              hipStream_t stream) {
  const float* x    = (const float*)d_in[0];
  const float* W_ih = (const float*)d_in[1];
  const float* W_hh = (const float*)d_in[2];
  const float* b_ih = (const float*)d_in[3];
  const float* b_hh = (const float*)d_in[4];
  float* out = (float*)d_out;
  hipLaunchKernelGGL(lstm_fused, dim3(256), dim3(512), 0, stream,
                     x, W_ih, W_hh, b_ih, b_hh, out);
}